// Round 4
// baseline (257.758 us; speedup 1.0000x reference)
//
#include <hip/hip_runtime.h>
#include <hip/hip_bf16.h>

#define NB 4096
#define MESH 778
#define JOUT (NB*MESH*3)
#define PI_F 3.14159265358979323846f

__device__ __forceinline__ void rodrigues(float x, float y, float z, float* R){
  float t2 = x*x + y*y + z*z;
  float th = sqrtf(t2);
  if (th < 1e-30f){
    float a = 1.0f - t2*(1.0f/6.0f);
    float b = 0.5f - t2*(1.0f/24.0f);
    R[0] = 1.0f + b*(x*x - t2); R[1] = -a*z + b*x*y;       R[2] = a*y + b*x*z;
    R[3] = a*z + b*x*y;         R[4] = 1.0f + b*(y*y - t2); R[5] = -a*x + b*y*z;
    R[6] = -a*y + b*x*z;        R[7] = a*x + b*y*z;        R[8] = 1.0f + b*(z*z - t2);
  } else {
    float inv = 1.0f / fmaxf(th, 1e-12f);
    float nx = x*inv, ny = y*inv, nz = z*inv;
    float s = sinf(th), c = cosf(th), ic = 1.0f - c;
    R[0] = c + ic*nx*nx;    R[1] = ic*nx*ny - s*nz; R[2] = ic*nx*nz + s*ny;
    R[3] = ic*ny*nx + s*nz; R[4] = c + ic*ny*ny;    R[5] = ic*ny*nz - s*nx;
    R[6] = ic*nz*nx - s*ny; R[7] = ic*nz*ny + s*nx; R[8] = c + ic*nz*nz;
  }
}

// ---- kJ: ws[j*33 + c*11 + k] = sum_m jreg[j][m] * sd[m][c][k]; k==10 -> v_template
__global__ __launch_bounds__(256) void kJ(const float* __restrict__ vt,
    const float* __restrict__ sd, const float* __restrict__ jreg,
    float* __restrict__ ws){
  int j = blockIdx.x;               // 16 blocks, one joint each
  int lane = threadIdx.x & 63, w = threadIdx.x >> 6;
  for (int combo = w; combo < 33; combo += 4){
    int c = combo / 11, k = combo - c*11;   // k==10 -> v_template
    float acc = 0.f;
    for (int m = lane; m < MESH; m += 64){
      float jr = jreg[j*MESH + m];
      float x = (k < 10) ? sd[(m*3 + c)*10 + k] : vt[m*3 + c];
      acc += jr * x;
    }
    #pragma unroll
    for (int off = 32; off; off >>= 1) acc += __shfl_down(acc, off, 64);
    if (lane == 0) ws[j*33 + combo] = acc;
  }
}

// ---- fused kernel: 32 batches x 16 vertices per block
__global__ __launch_bounds__(256) void kM(const float* __restrict__ root,
    const float* __restrict__ other, const float* __restrict__ bet,
    const float* __restrict__ vt, const float* __restrict__ sd,
    const float* __restrict__ pd, const float* __restrict__ wgt,
    const float* __restrict__ hc, const float* __restrict__ hm,
    const float* __restrict__ ws, float* __restrict__ out){
  __shared__ float s_pw[32*140];     // pose_w (R-I, 135 used +1 pad); later vout 32*49
  __shared__ float s_big[16*408];    // posedirs tile; later A^T (192*33=6334)
  __shared__ float s_vp[32*51];      // v_posed tile
  __shared__ float s_betas[32*12];
  __shared__ float s_sd[16*30];
  __shared__ float s_vt[48];
  __shared__ float s_w[256];
  __shared__ float s_rot[32*12];     // per-batch root rotation
  __shared__ float s_oth[32*6];
  __shared__ float s_js[528];        // Jt/JS from kJ

  int t = threadIdx.x;
  int m0 = blockIdx.x*16;
  int b0 = blockIdx.y*32;

  // ---------------- raw loads ----------------
  for (int idx=t; idx<16*408; idx+=256){
    int m = idx/408, r = idx - m*408;
    int c = r/136, p = r - c*136;
    float v = 0.f;
    if (p < 135 && (m0+m) < MESH) v = pd[((size_t)(m0+m)*3+c)*135 + p];
    s_big[m*408 + c*136 + p] = v;
  }
  for (int idx=t; idx<32*10; idx+=256){
    int i = idx/10, k = idx - i*10;
    s_betas[i*12+k] = bet[(b0+i)*10+k];
  }
  for (int idx=t; idx<16*30; idx+=256){
    int m = idx/30, r = idx - m*30;
    s_sd[m*30+r] = ((m0+m)<MESH) ? sd[(m0+m)*30 + r] : 0.f;
  }
  for (int idx=t; idx<48; idx+=256){
    int m = idx/3;
    s_vt[idx] = ((m0+m)<MESH) ? vt[m0*3 + idx] : 0.f;
  }
  for (int idx=t; idx<256; idx+=256){
    int m = idx/16;
    s_w[idx] = ((m0+m)<MESH) ? wgt[m0*16 + idx] : 0.f;
  }
  for (int idx=t; idx<192; idx+=256) s_oth[idx] = other[(size_t)b0*6 + idx];
  for (int idx=t; idx<528; idx+=256) s_js[idx] = ws[idx];
  __syncthreads();

  // ---------------- pose_w (15 rodrigues/batch) + root rot ----------------
  for (int task=t; task<512; task+=256){
    if (task < 480){
      int b = task/15, jj = task - b*15;     // joint jj+1
      int q0 = jj*3;
      float rx=hm[q0], ry=hm[q0+1], rz=hm[q0+2];
      #pragma unroll
      for (int u=0;u<6;++u){
        float o = s_oth[b*6+u];
        rx += o*hc[u*45+q0+0];
        ry += o*hc[u*45+q0+1];
        rz += o*hc[u*45+q0+2];
      }
      float Rl[9]; rodrigues(rx,ry,rz,Rl);
      float* pw = &s_pw[b*140 + jj*9];
      pw[0]=Rl[0]-1.f; pw[1]=Rl[1];     pw[2]=Rl[2];
      pw[3]=Rl[3];     pw[4]=Rl[4]-1.f; pw[5]=Rl[5];
      pw[6]=Rl[6];     pw[7]=Rl[7];     pw[8]=Rl[8]-1.f;
    } else {
      int b = task-480;
      float Rr[9];
      rodrigues(root[(b0+b)*3+0], root[(b0+b)*3+1], root[(b0+b)*3+2], Rr);
      #pragma unroll
      for (int e=0;e<9;++e) s_rot[b*12+e] = Rr[e];
      s_pw[b*140 + 135] = 0.f;   // float4 tail pad
    }
  }
  __syncthreads();

  // ---------------- phase 1: v_posed ----------------
  int bl = t & 31, mg = t >> 5;
  float acc[2][3];
  #pragma unroll
  for (int mi=0; mi<2; ++mi){
    int ml = mg*2+mi;
    #pragma unroll
    for (int c=0; c<3; ++c){
      float a = s_vt[ml*3+c];
      #pragma unroll
      for (int k=0;k<10;++k) a += s_betas[bl*12+k]*s_sd[ml*30+c*10+k];
      acc[mi][c]=a;
    }
  }
  const float4* pwv = reinterpret_cast<const float4*>(&s_pw[bl*140]);
  #pragma unroll 2
  for (int pq=0; pq<34; ++pq){
    float4 w = pwv[pq];
    #pragma unroll
    for (int mi=0; mi<2; ++mi){
      int ml = mg*2+mi;
      #pragma unroll
      for (int c=0;c<3;++c){
        float4 d = *reinterpret_cast<const float4*>(&s_big[ml*408 + c*136 + pq*4]);
        acc[mi][c] += w.x*d.x + w.y*d.y + w.z*d.z + w.w*d.w;
      }
    }
  }
  #pragma unroll
  for (int mi=0;mi<2;++mi){
    int ml=mg*2+mi;
    #pragma unroll
    for (int c=0;c<3;++c) s_vp[bl*51+ml*3+c] = acc[mi][c];
  }
  __syncthreads();

  // ---------------- mid-phase: kinematic chains -> A^T in s_big ----------------
  if (t < 160){
    int b = t/5, ch = t - b*5;
    int gb = b0 + b;
    float bt_[10];
    #pragma unroll
    for (int k=0;k<10;++k) bt_[k] = s_betas[b*12+k];
    float R0[9]; rodrigues(PI_F, 0.f, 0.f, R0);
    float J0[3];
    #pragma unroll
    for (int c=0;c<3;++c){
      float a = s_js[c*11 + 10];
      #pragma unroll
      for (int k=0;k<10;++k) a += bt_[k]*s_js[c*11 + k];
      J0[c]=a;
    }
    float Rot[9];
    #pragma unroll
    for (int e=0;e<9;++e) Rot[e] = s_rot[b*12+e];
    if (ch == 0){
      #pragma unroll
      for (int r=0;r<3;++r){
        float tr = J0[r];
        #pragma unroll
        for (int d=0;d<3;++d) tr -= R0[r*3+d]*J0[d];
        s_big[(r*4+0)*33 + b] = R0[r*3+0];
        s_big[(r*4+1)*33 + b] = R0[r*3+1];
        s_big[(r*4+2)*33 + b] = R0[r*3+2];
        s_big[(r*4+3)*33 + b] = tr;
      }
      if (blockIdx.x == 0){
        int base = JOUT + gb*63;
        #pragma unroll
        for (int c=0;c<3;++c)
          out[base+c] = Rot[c*3+0]*J0[0]+Rot[c*3+1]*J0[1]+Rot[c*3+2]*J0[2];
      }
    }
    float GpR[9], Gpt[3], Jp[3];
    #pragma unroll
    for (int e=0;e<9;++e) GpR[e]=R0[e];
    #pragma unroll
    for (int c=0;c<3;++c){ Gpt[c]=J0[c]; Jp[c]=J0[c]; }
    int start = 1 + ch*3;
    #pragma unroll 1
    for (int s=0;s<3;++s){
      int i = start+s;
      float Rl[9];
      #pragma unroll
      for (int e=0;e<9;++e){
        float v = s_pw[b*140 + (i-1)*9 + e];
        Rl[e] = (e==0||e==4||e==8) ? v+1.f : v;
      }
      float Ji[3];
      #pragma unroll
      for (int c=0;c<3;++c){
        float a = s_js[i*33 + c*11 + 10];
        #pragma unroll
        for (int k=0;k<10;++k) a += bt_[k]*s_js[i*33 + c*11 + k];
        Ji[c]=a;
      }
      float tl[3] = {Ji[0]-Jp[0], Ji[1]-Jp[1], Ji[2]-Jp[2]};
      float GR[9], Gt[3];
      #pragma unroll
      for (int r=0;r<3;++r){
        #pragma unroll
        for (int cc=0;cc<3;++cc)
          GR[r*3+cc] = GpR[r*3+0]*Rl[0*3+cc] + GpR[r*3+1]*Rl[1*3+cc] + GpR[r*3+2]*Rl[2*3+cc];
        Gt[r] = Gpt[r] + GpR[r*3+0]*tl[0] + GpR[r*3+1]*tl[1] + GpR[r*3+2]*tl[2];
      }
      #pragma unroll
      for (int r=0;r<3;++r){
        float tr = Gt[r] - (GR[r*3+0]*Ji[0] + GR[r*3+1]*Ji[1] + GR[r*3+2]*Ji[2]);
        s_big[(i*12 + r*4+0)*33 + b] = GR[r*3+0];
        s_big[(i*12 + r*4+1)*33 + b] = GR[r*3+1];
        s_big[(i*12 + r*4+2)*33 + b] = GR[r*3+2];
        s_big[(i*12 + r*4+3)*33 + b] = tr;
      }
      if (blockIdx.x == 0){
        int gx = i + (i>=4) + (i>=7) + (i>=10) + (i>=13);
        int base = JOUT + gb*63 + gx*3;
        #pragma unroll
        for (int c=0;c<3;++c)
          out[base+c] = Rot[c*3+0]*Gt[0]+Rot[c*3+1]*Gt[1]+Rot[c*3+2]*Gt[2];
      }
      #pragma unroll
      for (int e=0;e<9;++e) GpR[e]=GR[e];
      #pragma unroll
      for (int c=0;c<3;++c){ Gpt[c]=Gt[c]; Jp[c]=Ji[c]; }
    }
  }
  __syncthreads();

  // ---------------- phase 2: blend + skin + root rotation ----------------
  #pragma unroll
  for (int mi=0;mi<2;++mi){
    int ml = mg*2+mi; int m = m0+ml;
    float T[12];
    #pragma unroll
    for (int e=0;e<12;++e) T[e]=0.f;
    #pragma unroll
    for (int j=0;j<16;++j){
      float wj = s_w[ml*16+j];
      #pragma unroll
      for (int e=0;e<12;++e) T[e] += wj * s_big[(j*12+e)*33 + bl];
    }
    float vx = s_vp[bl*51+ml*3+0];
    float vy = s_vp[bl*51+ml*3+1];
    float vz = s_vp[bl*51+ml*3+2];
    float v0 = T[0]*vx+T[1]*vy+T[2]*vz+T[3];
    float v1 = T[4]*vx+T[5]*vy+T[6]*vz+T[7];
    float v2 = T[8]*vx+T[9]*vy+T[10]*vz+T[11];
    float r0 = s_rot[bl*12+0]*v0 + s_rot[bl*12+1]*v1 + s_rot[bl*12+2]*v2;
    float r1 = s_rot[bl*12+3]*v0 + s_rot[bl*12+4]*v1 + s_rot[bl*12+5]*v2;
    float r2 = s_rot[bl*12+6]*v0 + s_rot[bl*12+7]*v1 + s_rot[bl*12+8]*v2;
    s_pw[bl*49 + ml*3 + 0] = r0;   // vout overlays s_pw (pose_w no longer needed)
    s_pw[bl*49 + ml*3 + 1] = r1;
    s_pw[bl*49 + ml*3 + 2] = r2;
    if (m==333 || m==444 || m==672 || m==555 || m==745){
      int kt = (m==333)?4:(m==444)?8:(m==672)?12:(m==555)?16:20;
      int base = JOUT + (b0+bl)*63 + kt*3;
      out[base+0]=r0;
      out[base+1]=r1;
      out[base+2]=r2;
    }
  }
  __syncthreads();

  // ---------------- coalesced vertex write-out ----------------
  for (int idx=t; idx<32*48; idx+=256){
    int i = idx/48, r = idx - i*48;
    if (m0 + r/3 < MESH)
      out[(size_t)(b0+i)*(MESH*3) + m0*3 + r] = s_pw[i*49 + r];
  }
}

extern "C" void kernel_launch(void* const* d_in, const int* in_sizes, int n_in,
                              void* d_out, int out_size, void* d_ws, size_t ws_size,
                              hipStream_t stream) {
  const float* root  = (const float*)d_in[0];
  const float* other = (const float*)d_in[1];
  const float* bet   = (const float*)d_in[2];
  const float* vt    = (const float*)d_in[3];
  const float* sd    = (const float*)d_in[4];
  const float* pdirs = (const float*)d_in[5];
  const float* jreg  = (const float*)d_in[6];
  const float* wgt   = (const float*)d_in[7];
  const float* hc    = (const float*)d_in[8];
  const float* hm    = (const float*)d_in[9];
  float* ws = (float*)d_ws;
  float* out = (float*)d_out;

  kJ<<<dim3(16), dim3(256), 0, stream>>>(vt, sd, jreg, ws);
  kM<<<dim3(49, 128), dim3(256), 0, stream>>>(root, other, bet, vt, sd, pdirs,
                                              wgt, hc, hm, ws, out);
}